// Round 2
// baseline (1249.223 us; speedup 1.0000x reference)
//
#include <hip/hip_runtime.h>
#include <hip/hip_bf16.h>
#include <math.h>
#include <stdint.h>

#define ROI   116
#define FEATN 6670        // ROI*(ROI-1)/2
#define KP    6688        // FEATN padded to multiple of 32
#define DD    1024
#define HHN   1024
#define BB    64
#define WW    128
#define MT    8192        // BB*WW
#define XW    7694        // HHN + FEATN
#define EPSV  1e-5f
#define KB_SPLIT 32       // split-K blocks for skinny GEMMs
#define NTB   6688        // transpose blocks = (KP/32)*(DD/32) = 209*32
#define WS    4           // w-split factor for bagz

typedef __attribute__((ext_vector_type(8))) short short8;
typedef __attribute__((ext_vector_type(4))) float f32x4;
typedef __attribute__((ext_vector_type(4))) unsigned int u32x4;

typedef __attribute__((address_space(3))) unsigned int as3_u32;
typedef __attribute__((address_space(1))) unsigned int as1_u32;

// async global->LDS, 16B/lane. LDS dest must be lane-linear (wave base + lane*16).
__device__ __forceinline__ void gload_lds16(const void* g, void* l) {
  __builtin_amdgcn_global_load_lds(
      (const as1_u32*)(uintptr_t)g,
      (as3_u32*)(unsigned int)(uintptr_t)l,
      16, 0, 0);
}

__device__ __forceinline__ short f2bf(float v) {
  __hip_bfloat16 b = __float2bfloat16(v);
  return *reinterpret_cast<short*>(&b);
}

__device__ __forceinline__ float bf2f(short h) {
  unsigned int u = ((unsigned int)(unsigned short)h) << 16;
  float f;
  __builtin_memcpy(&f, &u, 4);
  return f;
}

__device__ __forceinline__ float fast_tanh(float x) {
  float ax = fabsf(x);
  float t  = __expf(-2.0f * ax);
  float r  = (1.0f - t) / (1.0f + t);
  return copysignf(r, x);
}

// ---- fused prep: blocks [0,MT) extract bag_level -> bf16 [MT][KP] (and zero a_out);
//      blocks [MT, MT+NTB) transpose W1 -> W1T (D x KP bf16). lut computed inline.
__global__ __launch_bounds__(256) void k_prep(const float* __restrict__ FC,
                                              const float* __restrict__ W1,
                                              short* __restrict__ bag,
                                              short* __restrict__ W1T,
                                              float* __restrict__ a_out) {
  __shared__ float tile[32][33];
  int bx = blockIdx.x;
  if (bx < MT) {
    int m = bx;
    if (threadIdx.x == 0) a_out[m] = 0.f;   // accumulator for fused h@W2 (atomics)
    const float* base = FC + (size_t)m * (ROI * ROI);
    for (int f0 = threadIdx.x * 8; f0 < KP; f0 += 2048) {
      // closed-form row index + fixup for f0 (walk 8 consecutive f)
      int fc = min(f0, FEATN - 1);
      int i = (int)((231.0f - sqrtf((float)(53361 - 8 * fc))) * 0.5f);
      i = max(0, min(i, ROI - 2));
      while (i > 0 && i * (231 - i) / 2 > fc) --i;
      while (i < ROI - 2 && (i + 1) * (231 - (i + 1)) / 2 <= fc) ++i;
      int j = i + 1 + (fc - i * (231 - i) / 2);
      short8 o;
#pragma unroll
      for (int e = 0; e < 8; e++) {
        float v = 0.f;
        if (f0 + e < FEATN) v = base[i * ROI + j];
        o[e] = f2bf(v);
        if (++j == ROI) { ++i; j = i + 1; }
      }
      *(short8*)(&bag[(size_t)m * KP + f0]) = o;
    }
  } else {
    int t2 = bx - MT;
    int k0 = (t2 % (KP / 32)) * 32;
    int d0 = (t2 / (KP / 32)) * 32;
    int tx = threadIdx.x & 31, ty = threadIdx.x >> 5;
    for (int r = 0; r < 32; r += 8) {
      int k = k0 + ty + r;
      float v = 0.f;
      if (k < FEATN) v = W1[(size_t)k * DD + d0 + tx];
      tile[ty + r][tx] = v;
    }
    __syncthreads();
    for (int r = 0; r < 32; r += 8)
      W1T[(size_t)(d0 + ty + r) * KP + k0 + tx] = f2bf(tile[tx][ty + r]);
  }
}

// ---- main GEMM: a[m] += sum_n tanh(bag@W1+b1)[m,n] * W2[n]  (H never hits HBM)
// 128x128 tile, bf16 MFMA 16x16x32, global_load_lds width-16 staging (m97 structure).
__global__ __launch_bounds__(256) void k_gemm(const short* __restrict__ A,
                                              const short* __restrict__ BT,
                                              const float* __restrict__ b1,
                                              const float* __restrict__ W2,
                                              float* __restrict__ a_out) {
  __shared__ __align__(16) short As[128][32];
  __shared__ __align__(16) short Bs[128][32];
  int tid  = threadIdx.x;
  int m0   = blockIdx.x * 128;
  int n0   = blockIdx.y * 128;
  int wave = tid >> 6, lane = tid & 63;
  int wr = wave >> 1, wc = wave & 1;
  int quad = lane >> 4, l15 = lane & 15;
  int srow = tid >> 2;
  int scol = (tid & 3) * 8;     // LDS byte off = tid*16 (lane-linear)

  f32x4 acc[4][4] = {};

  const short* Ag0 = A  + (size_t)(m0 + srow) * KP + scol;
  const short* Ag1 = Ag0 + (size_t)64 * KP;
  const short* Bg0 = BT + (size_t)(n0 + srow) * KP + scol;
  const short* Bg1 = Bg0 + (size_t)64 * KP;
  short* Al0 = &As[srow][scol];
  short* Al1 = &As[srow + 64][scol];
  short* Bl0 = &Bs[srow][scol];
  short* Bl1 = &Bs[srow + 64][scol];

  for (int k0 = 0; k0 < KP; k0 += 32) {
    gload_lds16(Ag0 + k0, Al0);
    gload_lds16(Ag1 + k0, Al1);
    gload_lds16(Bg0 + k0, Bl0);
    gload_lds16(Bg1 + k0, Bl1);
    __syncthreads();

    short8 af[4], bfm[4];
#pragma unroll
    for (int mi = 0; mi < 4; mi++)
      af[mi] = *(const short8*)(&As[wr * 64 + mi * 16 + l15][quad * 8]);
#pragma unroll
    for (int ni = 0; ni < 4; ni++)
      bfm[ni] = *(const short8*)(&Bs[wc * 64 + ni * 16 + l15][quad * 8]);
#pragma unroll
    for (int mi = 0; mi < 4; mi++)
#pragma unroll
      for (int ni = 0; ni < 4; ni++)
        acc[mi][ni] = __builtin_amdgcn_mfma_f32_16x16x32_bf16(af[mi], bfm[ni], acc[mi][ni], 0, 0, 0);
    __syncthreads();
  }

  // fused epilogue: tanh + dot with W2, reduce over this block's 128 n-columns.
  // b2 dropped: softmax is shift-invariant.
  float bias[4], w2v[4];
#pragma unroll
  for (int ni = 0; ni < 4; ni++) {
    int n = n0 + wc * 64 + ni * 16 + l15;
    bias[ni] = b1[n];
    w2v[ni]  = W2[n];
  }
#pragma unroll
  for (int mi = 0; mi < 4; mi++) {
#pragma unroll
    for (int r = 0; r < 4; r++) {
      float s = 0.f;
#pragma unroll
      for (int ni = 0; ni < 4; ni++)
        s += fast_tanh(acc[mi][ni][r] + bias[ni]) * w2v[ni];
      s += __shfl_xor(s, 1);
      s += __shfl_xor(s, 2);
      s += __shfl_xor(s, 4);
      s += __shfl_xor(s, 8);
      if (l15 == 0)
        atomicAdd(&a_out[m0 + wr * 64 + mi * 16 + quad * 4 + r], s);
    }
  }
}

// ---- fused softmax + attention-weighted bag sum, w-split WS-way ----
// bagzp[ws][b][f] = sum_{w in chunk ws} softmax(a)[b,w] * bag[(b,w)][f]
__global__ __launch_bounds__(256) void k_bagz(const short* __restrict__ bag,
                                              const float* __restrict__ abuf,
                                              float* __restrict__ bagzp) {
  __shared__ float sm[WW];
  __shared__ float red[64];
  int b = blockIdx.y, ws = blockIdx.z, t = threadIdx.x;
  if (t < WW) sm[t] = abuf[b * WW + t];
  __syncthreads();
  if (t < 64) red[t] = fmaxf(sm[t], sm[t + 64]);
  __syncthreads();
  for (int s = 32; s > 0; s >>= 1) { if (t < s) red[t] = fmaxf(red[t], red[t + s]); __syncthreads(); }
  float mx = red[0];
  __syncthreads();
  if (t < WW) sm[t] = expf(sm[t] - mx);
  __syncthreads();
  if (t < 64) red[t] = sm[t] + sm[t + 64];
  __syncthreads();
  for (int s = 32; s > 0; s >>= 1) { if (t < s) red[t] += red[t + s]; __syncthreads(); }
  float inv = 1.f / red[0];

  int f0 = blockIdx.x * 2048 + t * 8;
  if (f0 >= KP) return;
  const short* base = bag + ((size_t)b * WW + ws * (WW / WS)) * KP + f0;
  float s[8] = {};
  for (int w = 0; w < WW / WS; ++w) {
    float aw = sm[ws * (WW / WS) + w] * inv;
    short8 v = *(const short8*)(base + (size_t)w * KP);
#pragma unroll
    for (int e = 0; e < 8; e++) s[e] += aw * bf2f(v[e]);
  }
  float* dst = bagzp + ((size_t)ws * BB + b) * FEATN;
#pragma unroll
  for (int e = 0; e < 8; e++) {
    int f = f0 + e;
    if (f < FEATN) dst[f] = s[e];
  }
}

// ---- fused batchnorm: blocks [0,27) sum WS partials + bn over batch -> X[:, HHN+f];
//      blocks [27,54) batchnorm cluster_centers (2 rows) -> ccbn
__global__ void k_bnall(const float* __restrict__ bagzp, const float* __restrict__ g,
                        const float* __restrict__ beta, const float* __restrict__ cc,
                        const float* __restrict__ g2, const float* __restrict__ b2v,
                        float* __restrict__ X, float* __restrict__ ccbn) {
  int t = threadIdx.x;
  if (blockIdx.x < 27) {
    int f = blockIdx.x * 256 + t;
    if (f >= FEATN) return;
    float s = 0.f, s2 = 0.f;
#pragma unroll
    for (int b = 0; b < BB; b++) {
      float x = bagzp[(size_t)b * FEATN + f]
              + bagzp[((size_t)BB + b) * FEATN + f]
              + bagzp[((size_t)2 * BB + b) * FEATN + f]
              + bagzp[((size_t)3 * BB + b) * FEATN + f];
      s += x; s2 += x * x;
    }
    float mu  = s * (1.f / BB);
    float var = s2 * (1.f / BB) - mu * mu;
    float sc  = rsqrtf(var + EPSV) * g[f];
    float bt  = beta[f];
#pragma unroll
    for (int b = 0; b < BB; b++) {
      float x = bagzp[(size_t)b * FEATN + f]
              + bagzp[((size_t)BB + b) * FEATN + f]
              + bagzp[((size_t)2 * BB + b) * FEATN + f]
              + bagzp[((size_t)3 * BB + b) * FEATN + f];
      X[(size_t)b * XW + HHN + f] = (x - mu) * sc + bt;
    }
  } else {
    int f = (blockIdx.x - 27) * 256 + t;
    if (f >= FEATN) return;
    float c0 = cc[f], c1 = cc[FEATN + f];
    float mu = 0.5f * (c0 + c1);
    float d0 = c0 - mu, d1 = c1 - mu;
    float var = 0.5f * (d0 * d0 + d1 * d1);
    float sc = rsqrtf(var + EPSV) * g2[f];
    ccbn[f]         = d0 * sc + b2v[f];
    ccbn[FEATN + f] = d1 * sc + b2v[f];
  }
}

// ---- skinny fp32 GEMM body, spill-free: 64 n-cols x 4 row-groups per block ----
template <int R, int MODE>
__device__ __forceinline__ void skinny_body(const float* __restrict__ X,
                                            const float* __restrict__ ccbn,
                                            const float* __restrict__ Wt,
                                            float* __restrict__ partial,
                                            int K, int kchunk) {
  constexpr int RG = (R + 3) / 4;
  constexpr int RP = RG * 4;
  __shared__ __align__(16) float zs[RP][68];
  int tx = threadIdx.x & 63;
  int ty = threadIdx.x >> 6;
  int n  = blockIdx.x * 64 + tx;
  int k0 = blockIdx.y * kchunk;
  int k1 = min(k0 + kchunk, K);
  int r0 = ty * RG;

  float acc[RG];
#pragma unroll
  for (int i = 0; i < RG; i++) acc[i] = 0.f;

  for (int kk0 = k0; kk0 < k1; kk0 += 64) {
    for (int idx = threadIdx.x; idx < RP * 64; idx += 256) {
      int r = idx >> 6, c = idx & 63;
      int k = kk0 + c;
      float v = 0.f;
      if (r < R && k < k1) {
        const float* zr;
        if (MODE == 0) zr = (r < 64) ? (X + (size_t)r * XW + HHN) : (ccbn + (size_t)(r - 64) * FEATN);
        else if (MODE == 1) zr = ccbn + (size_t)r * FEATN;
        else zr = X + (size_t)r * XW;
        v = zr[k];
      }
      zs[r][c] = v;
    }
    __syncthreads();
#pragma unroll 4
    for (int c = 0; c < 64; c += 4) {
      int k = kk0 + c;
      float w0 = (k + 0 < k1) ? Wt[(size_t)(k + 0) * HHN + n] : 0.f;
      float w1 = (k + 1 < k1) ? Wt[(size_t)(k + 1) * HHN + n] : 0.f;
      float w2 = (k + 2 < k1) ? Wt[(size_t)(k + 2) * HHN + n] : 0.f;
      float w3 = (k + 3 < k1) ? Wt[(size_t)(k + 3) * HHN + n] : 0.f;
#pragma unroll
      for (int i = 0; i < RG; i++) {
        f32x4 z = *(const f32x4*)(&zs[r0 + i][c]);
        acc[i] += z.x * w0 + z.y * w1 + z.z * w2 + z.w * w3;
      }
    }
    __syncthreads();
  }
#pragma unroll
  for (int i = 0; i < RG; i++) {
    int rr = r0 + i;
    if (rr < R)
      partial[(size_t)blockIdx.y * R * HHN + (size_t)rr * HHN + n] = acc[i];
  }
}

// ---- fused Q+K skinny GEMM: z=0 -> [X;ccbn]@Wq (66 rows), z=1 -> ccbn@Wk (2 rows)
__global__ __launch_bounds__(256) void k_qk(const float* __restrict__ X,
                                            const float* __restrict__ ccbn,
                                            const float* __restrict__ Wq,
                                            const float* __restrict__ Wk,
                                            float* __restrict__ partQ,
                                            float* __restrict__ partK) {
  if (blockIdx.z == 0) skinny_body<66, 0>(X, ccbn, Wq, partQ, FEATN, 209);
  else                 skinny_body<2, 1>(X, ccbn, Wk, partK, FEATN, 209);
}

// ---- C-path skinny GEMM (X @ Wc1, K=XW) ----
__global__ __launch_bounds__(256) void k_skinnyC(const float* __restrict__ X,
                                                 const float* __restrict__ Wt,
                                                 float* __restrict__ partial) {
  skinny_body<64, 2>(X, nullptr, Wt, partial, XW, 241);
}

// ---- fused reduce for Q (66*HHN) and K (2*HHN) partials ----
__global__ void k_redqk(const float* __restrict__ partQ, const float* __restrict__ partK,
                        const float* __restrict__ bq, const float* __restrict__ bk,
                        float* __restrict__ qv, float* __restrict__ kb) {
  int idx = blockIdx.x * 256 + threadIdx.x;
  if (idx < 66 * HHN) {
    int n = idx & (HHN - 1);
    float s = bq[n];
    for (int kbk = 0; kbk < KB_SPLIT; kbk++) s += partQ[(size_t)kbk * 66 * HHN + idx];
    qv[idx] = s;
  } else {
    int id2 = idx - 66 * HHN;
    int n = id2 & (HHN - 1);
    float s = bk[n];
    for (int kbk = 0; kbk < KB_SPLIT; kbk++) s += partK[(size_t)kbk * 2 * HHN + id2];
    kb[id2] = s;
  }
}

// ---- reduce split-K partials, add bias, relu (C path) ----
template <int R>
__global__ void k_reduce(const float* __restrict__ partial, const float* __restrict__ bias,
                         float* __restrict__ out, int KB, int act) {
  int idx = blockIdx.x * 256 + threadIdx.x;
  if (idx >= R * HHN) return;
  int n = idx & (HHN - 1);
  float s = bias[n];
  for (int kb = 0; kb < KB; kb++) s += partial[(size_t)kb * R * HHN + idx];
  if (act) s = fmaxf(s, 0.f);
  out[idx] = s;
}

// ---- cross attention: QK softmax over 2 centers, write final_cross into X[:, :HHN] ----
__global__ void k_cross(const float* __restrict__ qv, const float* __restrict__ kb,
                        float* __restrict__ X) {
  int b = blockIdx.x, t = threadIdx.x;
  const float* q  = qv + (size_t)b * HHN;
  const float* v0 = qv + (size_t)64 * HHN;
  const float* v1 = qv + (size_t)65 * HHN;
  float s0 = 0.f, s1 = 0.f;
  for (int n = t; n < HHN; n += 256) {
    float qn = q[n];
    s0 += qn * kb[n];
    s1 += qn * kb[HHN + n];
  }
  __shared__ float r0[256], r1[256];
  r0[t] = s0; r1[t] = s1; __syncthreads();
  for (int st = 128; st > 0; st >>= 1) {
    if (t < st) { r0[t] += r0[t + st]; r1[t] += r1[t + st]; }
    __syncthreads();
  }
  float d0 = r0[0] * (1.f / 32.f), d1 = r1[0] * (1.f / 32.f);
  float mx = fmaxf(d0, d1);
  float e0 = expf(d0 - mx), e1 = expf(d1 - mx);
  float p0 = e0 / (e0 + e1), p1 = e1 / (e0 + e1);
  for (int n = t; n < HHN; n += 256)
    X[(size_t)b * XW + n] = p0 * v0[n] + p1 * v1[n];
}

// ---- final: y = relu_out @ Wc2 + bc2 -> sigmoid -> (prob, hat) ----
__global__ void k_final(const float* __restrict__ Rb, const float* __restrict__ Wc2,
                        const float* __restrict__ bc2, float* __restrict__ out) {
  int b = blockIdx.x, t = threadIdx.x;
  float s = 0.f;
  for (int n = t; n < HHN; n += 256) s += Rb[(size_t)b * HHN + n] * Wc2[n];
  __shared__ float red[256];
  red[t] = s; __syncthreads();
  for (int st = 128; st > 0; st >>= 1) {
    if (t < st) red[t] += red[t + st];
    __syncthreads();
  }
  if (t == 0) {
    float y = red[0] + bc2[0];
    float p = 1.f / (1.f + expf(-y));
    out[b]      = p;
    out[64 + b] = (p >= 0.5f) ? 1.f : 0.f;
  }
}

extern "C" void kernel_launch(void* const* d_in, const int* in_sizes, int n_in,
                              void* d_out, int out_size, void* d_ws, size_t ws_size,
                              hipStream_t stream) {
  const float* FC    = (const float*)d_in[0];
  const float* CC    = (const float*)d_in[1];
  const float* W1    = (const float*)d_in[2];
  const float* b1    = (const float*)d_in[3];
  const float* W2    = (const float*)d_in[4];
  const float* b2    = (const float*)d_in[5];
  const float* bn_g  = (const float*)d_in[6];
  const float* bn_b  = (const float*)d_in[7];
  const float* bn2_g = (const float*)d_in[8];
  const float* bn2_b = (const float*)d_in[9];
  const float* Wq    = (const float*)d_in[10];
  const float* bq    = (const float*)d_in[11];
  const float* Wk    = (const float*)d_in[12];
  const float* bk    = (const float*)d_in[13];
  const float* Wc1   = (const float*)d_in[14];
  const float* bc1   = (const float*)d_in[15];
  const float* Wc2   = (const float*)d_in[16];
  const float* bc2   = (const float*)d_in[17];
  float* out = (float*)d_out;
  (void)b2;  // softmax shift-invariant: b2 provably cancels

  char* w = (char*)d_ws;
  auto alloc = [&](size_t bytes) {
    char* p = w;
    w += (bytes + 255) & ~(size_t)255;
    return p;
  };
  short* bagbf   = (short*)alloc((size_t)MT * KP * 2);        // 109.6 MB
  short* W1T     = (short*)alloc((size_t)DD * KP * 2);        // 13.7 MB
  float* abuf    = (float*)alloc((size_t)MT * 4);
  float* bagzp   = (float*)alloc((size_t)WS * BB * FEATN * 4); // 6.83 MB
  float* Xbuf    = (float*)alloc((size_t)BB * XW * 4);
  float* ccbn    = (float*)alloc((size_t)2 * FEATN * 4);
  float* qvbuf   = (float*)alloc((size_t)66 * HHN * 4);
  float* kbuf    = (float*)alloc((size_t)2 * HHN * 4);
  float* Rbuf    = (float*)alloc((size_t)BB * HHN * 4);
  float* partQ   = (float*)alloc((size_t)KB_SPLIT * 66 * HHN * 4);  // 8.65 MB (reused as partC)
  float* partK   = (float*)alloc((size_t)KB_SPLIT * 2 * HHN * 4);
  float* partC   = partQ;   // alias: partQ dead before partC written

  k_prep<<<dim3(MT + NTB), dim3(256), 0, stream>>>(FC, W1, bagbf, W1T, abuf);
  k_gemm<<<dim3(MT / 128, DD / 128), dim3(256), 0, stream>>>(bagbf, W1T, b1, W2, abuf);
  k_bagz<<<dim3(4, BB, WS), dim3(256), 0, stream>>>(bagbf, abuf, bagzp);
  k_bnall<<<dim3(54), dim3(256), 0, stream>>>(bagzp, bn_g, bn_b, CC, bn2_g, bn2_b, Xbuf, ccbn);

  k_qk<<<dim3(16, KB_SPLIT, 2), dim3(256), 0, stream>>>(Xbuf, ccbn, Wq, Wk, partQ, partK);
  k_redqk<<<dim3(68 * HHN / 256), dim3(256), 0, stream>>>(partQ, partK, bq, bk, qvbuf, kbuf);
  k_cross<<<dim3(BB), dim3(256), 0, stream>>>(qvbuf, kbuf, Xbuf);

  k_skinnyC<<<dim3(16, KB_SPLIT), dim3(256), 0, stream>>>(Xbuf, Wc1, partC);
  k_reduce<64><<<dim3(64 * HHN / 256), dim3(256), 0, stream>>>(partC, bc1, Rbuf, KB_SPLIT, 1);
  k_final<<<dim3(BB), dim3(256), 0, stream>>>(Rbuf, Wc2, bc2, out);

  (void)in_sizes; (void)n_in; (void)out_size; (void)ws_size;
}